// Round 3
// baseline (109.041 us; speedup 1.0000x reference)
//
#include <hip/hip_runtime.h>
#include <math.h>

// Problem constants (fixed by setup_inputs)
#define B_  16
#define C_  512
#define CR_ 128
#define N_  4096
#define CSPLIT 8
#define CCHUNK (C_ / CSPLIT)   // 64 rows per partial

static constexpr float BN_EPS_F = 1e-5f;

// Native clang vector type (HIP's float4 is a class — rejected by
// __builtin_nontemporal_store).
typedef float vfloat4 __attribute__((ext_vector_type(4)));

// ---------------------------------------------------------------------------
// K1: partial channel colsum, float4.
// s_part[cs][b][n] = sum_{c in chunk cs} x[b,c,n]
// grid = (N/1024, B, CSPLIT) = (4,16,8) = 512 blocks, block = 256.
// Each thread owns one float4 column; 64 coalesced float4 row-reads.
// ---------------------------------------------------------------------------
__global__ void k1_colsum_part(const float* __restrict__ x,
                               float* __restrict__ s_part) {
    const int n4 = blockIdx.x * 256 + threadIdx.x;       // [0, N/4)
    const int b  = blockIdx.y;
    const int cs = blockIdx.z;
    const vfloat4* xp = (const vfloat4*)(x + ((size_t)b * C_ + (size_t)cs * CCHUNK) * N_) + n4;
    vfloat4 acc = {0.f, 0.f, 0.f, 0.f};
#pragma unroll 8
    for (int c = 0; c < CCHUNK; ++c)
        acc += xp[(size_t)c * (N_ / 4)];
    ((vfloat4*)s_part)[((size_t)cs * B_ + b) * (N_ / 4) + n4] = acc;
}

// ---------------------------------------------------------------------------
// K1b: s[b,n] = sum_cs s_part[cs][b][n]   (B*N/4 = 16384 float4s)
// ---------------------------------------------------------------------------
__global__ void k1b_reduce(const float* __restrict__ s_part,
                           float* __restrict__ s) {
    const int i4 = blockIdx.x * 256 + threadIdx.x;       // [0, B*N/4)
    const vfloat4* sp = (const vfloat4*)s_part;
    vfloat4 acc = {0.f, 0.f, 0.f, 0.f};
#pragma unroll
    for (int cs = 0; cs < CSPLIT; ++cs)
        acc += sp[(size_t)cs * (B_ * N_ / 4) + i4];
    ((vfloat4*)s)[i4] = acc;
}

// ---------------------------------------------------------------------------
// K2: att[b,c] = sum_n x[b,c,n] * s[b,n].  One wave per row.
// block = 256 (4 waves), grid = B*C/4 = 2048.  x should be L3-resident.
// ---------------------------------------------------------------------------
__global__ void k2_att(const float* __restrict__ x,
                       const float* __restrict__ s,
                       float* __restrict__ att) {
    const int wave = threadIdx.x >> 6;
    const int lane = threadIdx.x & 63;
    const int row  = blockIdx.x * 4 + wave;   // [0, B*C)
    const int b    = row >> 9;                // row / C_
    const vfloat4* xp = (const vfloat4*)(x + (size_t)row * N_);
    const vfloat4* sp = (const vfloat4*)(s + (size_t)b * N_);
    float acc0 = 0.f, acc1 = 0.f;
#pragma unroll
    for (int k = 0; k < N_ / 4 / 64; k += 2) {   // 16 iters, 2 accumulators
        vfloat4 xv0 = xp[k * 64 + lane];
        vfloat4 sv0 = sp[k * 64 + lane];
        vfloat4 xv1 = xp[(k + 1) * 64 + lane];
        vfloat4 sv1 = sp[(k + 1) * 64 + lane];
        acc0 += xv0.x * sv0.x + xv0.y * sv0.y + xv0.z * sv0.z + xv0.w * sv0.w;
        acc1 += xv1.x * sv1.x + xv1.y * sv1.y + xv1.z * sv1.z + xv1.w * sv1.w;
    }
    float acc = acc0 + acc1;
#pragma unroll
    for (int off = 32; off >= 1; off >>= 1)
        acc += __shfl_down(acc, off, 64);
    if (lane == 0) att[row] = acc;
}

// ---------------------------------------------------------------------------
// K3: fused dense1+BN+ReLU+dense2+sigmoid.  One block per batch b.
// Phase A: att[b,:] -> LDS; 128 threads compute h[b,o] (512-dot).
// Phase B: 256 threads compute 2 outputs each of a[b,j] (128-dot vs LDS h).
// ---------------------------------------------------------------------------
__global__ void k3_fused(const float* __restrict__ W1,
                         const float* __restrict__ att,
                         const float* __restrict__ gamma,
                         const float* __restrict__ beta,
                         const float* __restrict__ rmean,
                         const float* __restrict__ rvar,
                         const float* __restrict__ W2,
                         float* __restrict__ a) {
    __shared__ float att_s[C_];
    __shared__ float h_s[CR_];
    const int b = blockIdx.x;
    const int t = threadIdx.x;
    // load att[b,:] (512 floats) into LDS
    for (int i = t; i < C_; i += 256) att_s[i] = att[(size_t)b * C_ + i];
    __syncthreads();
    if (t < CR_) {
        const float* w = W1 + (size_t)t * C_;
        float a0 = 0.f, a1 = 0.f, a2 = 0.f, a3 = 0.f;
#pragma unroll 4
        for (int c = 0; c < C_; c += 4) {
            a0 += w[c + 0] * att_s[c + 0];
            a1 += w[c + 1] * att_s[c + 1];
            a2 += w[c + 2] * att_s[c + 2];
            a3 += w[c + 3] * att_s[c + 3];
        }
        float acc = (a0 + a1) + (a2 + a3);
        float v = gamma[t] * (acc - rmean[t]) * rsqrtf(rvar[t] + BN_EPS_F) + beta[t];
        h_s[t] = fmaxf(v, 0.f);
    }
    __syncthreads();
#pragma unroll
    for (int j0 = 0; j0 < C_; j0 += 256) {
        const int j = j0 + t;
        const float* w = W2 + (size_t)j * CR_;
        float a0 = 0.f, a1 = 0.f, a2 = 0.f, a3 = 0.f;
#pragma unroll 4
        for (int k = 0; k < CR_; k += 4) {
            a0 += w[k + 0] * h_s[k + 0];
            a1 += w[k + 1] * h_s[k + 1];
            a2 += w[k + 2] * h_s[k + 2];
            a3 += w[k + 3] * h_s[k + 3];
        }
        float acc = (a0 + a1) + (a2 + a3);
        a[(size_t)b * C_ + j] = 1.f / (1.f + expf(-acc));
    }
}

// ---------------------------------------------------------------------------
// K4: out[b,c,n] = x[b,c,n] * a[b,c].  float4 grid-stride, NT stores.
// ---------------------------------------------------------------------------
__global__ void k4_scale(const float* __restrict__ x,
                         const float* __restrict__ a,
                         float* __restrict__ out) {
    const size_t total4 = (size_t)B_ * C_ * N_ / 4;
    const size_t stride = (size_t)gridDim.x * blockDim.x;
    for (size_t i = (size_t)blockIdx.x * blockDim.x + threadIdx.x;
         i < total4; i += stride) {
        const size_t row = i >> 10;           // / (N_/4)
        const float av = a[row];
        vfloat4 xv = ((const vfloat4*)x)[i];
        vfloat4 ov = xv * av;
        __builtin_nontemporal_store(ov, &((vfloat4*)out)[i]);
    }
}

// ---------------------------------------------------------------------------
extern "C" void kernel_launch(void* const* d_in, const int* in_sizes, int n_in,
                              void* d_out, int out_size, void* d_ws, size_t ws_size,
                              hipStream_t stream) {
    const float* x     = (const float*)d_in[0];
    const float* W1    = (const float*)d_in[1];
    const float* gamma = (const float*)d_in[2];
    const float* beta  = (const float*)d_in[3];
    const float* rmean = (const float*)d_in[4];
    const float* rvar  = (const float*)d_in[5];
    const float* W2    = (const float*)d_in[6];
    float* out = (float*)d_out;

    // Workspace layout (floats)
    float* ws     = (float*)d_ws;
    float* s_part = ws;                                  // CSPLIT*B*N = 524288
    float* s      = s_part + (size_t)CSPLIT * B_ * N_;   // B*N = 65536
    float* att    = s + (size_t)B_ * N_;                 // B*C = 8192
    float* a      = att + (size_t)B_ * C_;                // B*C = 8192

    k1_colsum_part<<<dim3(N_ / 1024, B_, CSPLIT), 256, 0, stream>>>(x, s_part);
    k1b_reduce<<<dim3(B_ * N_ / 1024), 256, 0, stream>>>(s_part, s);
    k2_att<<<dim3(B_ * C_ / 4), 256, 0, stream>>>(x, s, att);
    k3_fused<<<dim3(B_), 256, 0, stream>>>(W1, att, gamma, beta, rmean, rvar, W2, a);
    k4_scale<<<dim3(2048), 256, 0, stream>>>(x, a, out);
}

// Round 6
// 90.333 us; speedup vs baseline: 1.2071x; 1.2071x over previous
//
#include <hip/hip_runtime.h>
#include <math.h>

// Problem constants (fixed by setup_inputs)
#define B_   16
#define C_   512
#define CR_  128
#define N_   4096
#define N4_  (N_ / 4)        // 1024 float4 per row
#define TN   32              // tile width in floats
#define TN4  (TN / 4)        // 8 float4 per tile-row
#define SUBT 4               // subtiles per block
#define NTB  (N_ / TN / SUBT)  // 32 tile-blocks per batch

static constexpr float BN_EPS_F = 1e-5f;

typedef float vfloat4 __attribute__((ext_vector_type(4)));

// ---------------------------------------------------------------------------
// K1f: fused colsum + att partials.  ONE pass over x.
// Block (ntb, b): 4 subtiles of 32 columns each.  Per subtile:
//   - thread t (g=t>>3 in [0,32), i=t&7 in [0,8)) loads rows c=st*32+g,
//     f4-col i into v[16] registers, accumulating colsum partial sacc.
//   - LDS reduce sacc over g -> s_tile (32 cols of s, complete: all 512 ch).
//   - att contribution: dot4(v[st], s4(i)) reduced over i via shfl_xor(1,2,4);
//     lane i==0 accumulates att_s[c] in LDS across subtiles.
// Writes att_part[ntb][b][c] (32x16x512 floats = 1 MiB).
// ---------------------------------------------------------------------------
__global__ __launch_bounds__(256) void k1f_att(
        const float* __restrict__ x,
        float* __restrict__ att_part) {
    const int ntb = blockIdx.x;          // [0, 32)
    const int b   = blockIdx.y;          // [0, 16)
    const int t   = threadIdx.x;
    const int g   = t >> 3;              // [0, 32)  row-group
    const int i   = t & 7;               // [0, 8)   f4 column

    __shared__ vfloat4 s_red[32][8];
    __shared__ vfloat4 s_tile4[8];
    __shared__ float   att_s[C_];

    att_s[t] = 0.f;
    att_s[t + 256] = 0.f;

    const vfloat4* x4 = (const vfloat4*)x;

    for (int sub = 0; sub < SUBT; ++sub) {
        const int nt = ntb * SUBT + sub;
        const vfloat4* base = x4 + (size_t)b * C_ * N4_ + (size_t)nt * TN4;
        vfloat4 v[16];
        vfloat4 sacc = {0.f, 0.f, 0.f, 0.f};
#pragma unroll
        for (int st = 0; st < 16; ++st) {
            v[st] = base[(size_t)(st * 32 + g) * N4_ + i];
            sacc += v[st];
        }
        __syncthreads();                 // s_red safe to overwrite
        s_red[g][i] = sacc;
        __syncthreads();
        if (t < 8) {
            vfloat4 acc = {0.f, 0.f, 0.f, 0.f};
#pragma unroll
            for (int g2 = 0; g2 < 32; ++g2)
                acc += s_red[g2][t];
            s_tile4[t] = acc;
        }
        __syncthreads();
        const vfloat4 sv = s_tile4[i];
#pragma unroll
        for (int st = 0; st < 16; ++st) {
            float d = v[st].x * sv.x + v[st].y * sv.y
                    + v[st].z * sv.z + v[st].w * sv.w;
            d += __shfl_xor(d, 1, 64);
            d += __shfl_xor(d, 2, 64);
            d += __shfl_xor(d, 4, 64);   // sum over i within 8-lane group
            if (i == 0) att_s[st * 32 + g] += d;
        }
    }
    __syncthreads();
    float* dst = att_part + ((size_t)ntb * B_ + b) * C_;
    dst[t]       = att_s[t];
    dst[t + 256] = att_s[t + 256];
}

// ---------------------------------------------------------------------------
// K3f: att-partial reduce + dense1 + BN + ReLU + dense2 + sigmoid.
// One block per batch b (16 blocks, 256 threads).
// ---------------------------------------------------------------------------
__global__ void k3f(const float* __restrict__ att_part,
                    const float* __restrict__ W1,
                    const float* __restrict__ gamma,
                    const float* __restrict__ beta,
                    const float* __restrict__ rmean,
                    const float* __restrict__ rvar,
                    const float* __restrict__ W2,
                    float* __restrict__ a) {
    __shared__ float att_s[C_];
    __shared__ float h_s[CR_];
    const int b = blockIdx.x;
    const int t = threadIdx.x;

    // reduce 32 tile-partials -> att[b, :]
    {
        float a0 = 0.f, a1 = 0.f;
#pragma unroll 8
        for (int nb = 0; nb < NTB; ++nb) {
            const float* p = att_part + ((size_t)nb * B_ + b) * C_;
            a0 += p[t];
            a1 += p[t + 256];
        }
        att_s[t]       = a0;
        att_s[t + 256] = a1;
    }
    __syncthreads();

    if (t < CR_) {
        const float* w = W1 + (size_t)t * C_;
        float a0 = 0.f, a1 = 0.f, a2 = 0.f, a3 = 0.f;
#pragma unroll 4
        for (int c = 0; c < C_; c += 4) {
            a0 += w[c + 0] * att_s[c + 0];
            a1 += w[c + 1] * att_s[c + 1];
            a2 += w[c + 2] * att_s[c + 2];
            a3 += w[c + 3] * att_s[c + 3];
        }
        float acc = (a0 + a1) + (a2 + a3);
        float vv = gamma[t] * (acc - rmean[t]) * rsqrtf(rvar[t] + BN_EPS_F) + beta[t];
        h_s[t] = fmaxf(vv, 0.f);
    }
    __syncthreads();
#pragma unroll
    for (int j0 = 0; j0 < C_; j0 += 256) {
        const int j = j0 + t;
        const float* w = W2 + (size_t)j * CR_;
        float a0 = 0.f, a1 = 0.f, a2 = 0.f, a3 = 0.f;
#pragma unroll 4
        for (int k = 0; k < CR_; k += 4) {
            a0 += w[k + 0] * h_s[k + 0];
            a1 += w[k + 1] * h_s[k + 1];
            a2 += w[k + 2] * h_s[k + 2];
            a3 += w[k + 3] * h_s[k + 3];
        }
        float acc = (a0 + a1) + (a2 + a3);
        a[(size_t)b * C_ + j] = 1.f / (1.f + expf(-acc));
    }
}

// ---------------------------------------------------------------------------
// K4: out[b,c,n] = x[b,c,n] * a[b,c].  float4 grid-stride, NT stores.
// ---------------------------------------------------------------------------
__global__ void k4_scale(const float* __restrict__ x,
                         const float* __restrict__ a,
                         float* __restrict__ out) {
    const size_t total4 = (size_t)B_ * C_ * N_ / 4;
    const size_t stride = (size_t)gridDim.x * blockDim.x;
    for (size_t idx = (size_t)blockIdx.x * blockDim.x + threadIdx.x;
         idx < total4; idx += stride) {
        const size_t row = idx >> 10;           // / (N/4)
        const float av = a[row];
        vfloat4 xv = ((const vfloat4*)x)[idx];
        vfloat4 ov = xv * av;
        __builtin_nontemporal_store(ov, &((vfloat4*)out)[idx]);
    }
}

// ---------------------------------------------------------------------------
extern "C" void kernel_launch(void* const* d_in, const int* in_sizes, int n_in,
                              void* d_out, int out_size, void* d_ws, size_t ws_size,
                              hipStream_t stream) {
    const float* x     = (const float*)d_in[0];
    const float* W1    = (const float*)d_in[1];
    const float* gamma = (const float*)d_in[2];
    const float* beta  = (const float*)d_in[3];
    const float* rmean = (const float*)d_in[4];
    const float* rvar  = (const float*)d_in[5];
    const float* W2    = (const float*)d_in[6];
    float* out = (float*)d_out;

    // Workspace (floats): att_part 32*16*512 = 262144 (1 MiB), a 8192 (32 KiB)
    float* ws       = (float*)d_ws;
    float* att_part = ws;
    float* a        = att_part + (size_t)NTB * B_ * C_;

    k1f_att<<<dim3(NTB, B_), 256, 0, stream>>>(x, att_part);
    k3f<<<dim3(B_), 256, 0, stream>>>(att_part, W1, gamma, beta, rmean, rvar, W2, a);
    k4_scale<<<dim3(2048), 256, 0, stream>>>(x, a, out);
}

// Round 7
// 88.291 us; speedup vs baseline: 1.2350x; 1.0231x over previous
//
#include <hip/hip_runtime.h>
#include <math.h>

// Problem constants (fixed by setup_inputs)
#define B_   16
#define C_   512
#define CR_  128
#define N_   4096
#define N4_  (N_ / 4)          // 1024 float4 per row
#define TN   32                // tile width in floats
#define TN4  (TN / 4)          // 8 float4 per tile-row
#define SUBT 2                 // subtiles per block
#define NTB  (N_ / TN / SUBT)  // 64 tile-blocks per batch -> 1024 blocks

static constexpr float BN_EPS_F = 1e-5f;

typedef float vfloat4 __attribute__((ext_vector_type(4)));

// ---------------------------------------------------------------------------
// K1f: fused colsum + att partials.  ONE pass over x.
// Block (ntb, b), thread t: g=t>>3 (row-group 0..31), i=t&7 (f4 col 0..7).
// Per subtile: load 16 rows (c=st*32+g) x 1 f4 -> v[16]; LDS-reduce column
// sums over g -> s_tile (complete s for these 32 n's: all 512 channels in
// tile); accumulate dacc[st] += dot4(v[st], s) across subtiles.
// Tail: 8-lane shfl reduce over i, lane i==0 writes att_part[ntb][b][c].
// ---------------------------------------------------------------------------
__global__ __launch_bounds__(256) void k1f_att(
        const float* __restrict__ x,
        float* __restrict__ att_part) {
    const int ntb = blockIdx.x;          // [0, NTB)
    const int b   = blockIdx.y;          // [0, 16)
    const int t   = threadIdx.x;
    const int g   = t >> 3;              // [0, 32)
    const int i   = t & 7;               // [0, 8)

    __shared__ vfloat4 s_red[32][8];
    __shared__ vfloat4 s_tile4[8];

    const vfloat4* x4 = (const vfloat4*)x;
    float dacc[16];
#pragma unroll
    for (int st = 0; st < 16; ++st) dacc[st] = 0.f;

    for (int sub = 0; sub < SUBT; ++sub) {
        const int nt = ntb * SUBT + sub;
        const vfloat4* base = x4 + (size_t)b * C_ * N4_ + (size_t)nt * TN4;
        vfloat4 v[16];
        vfloat4 sacc = {0.f, 0.f, 0.f, 0.f};
#pragma unroll
        for (int st = 0; st < 16; ++st) {
            v[st] = base[(size_t)(st * 32 + g) * N4_ + i];
            sacc += v[st];
        }
        if (sub) __syncthreads();        // protect s_red/s_tile4 reuse
        s_red[g][i] = sacc;
        __syncthreads();
        if (t < 8) {
            vfloat4 acc = {0.f, 0.f, 0.f, 0.f};
#pragma unroll
            for (int g2 = 0; g2 < 32; ++g2)
                acc += s_red[g2][t];
            s_tile4[t] = acc;
        }
        __syncthreads();
        const vfloat4 sv = s_tile4[i];
#pragma unroll
        for (int st = 0; st < 16; ++st)
            dacc[st] += v[st].x * sv.x + v[st].y * sv.y
                      + v[st].z * sv.z + v[st].w * sv.w;
    }

    // reduce dacc over the 8-lane i group; lane i==0 owns c = st*32+g
#pragma unroll
    for (int st = 0; st < 16; ++st) {
        float d = dacc[st];
        d += __shfl_xor(d, 1, 64);
        d += __shfl_xor(d, 2, 64);
        d += __shfl_xor(d, 4, 64);
        dacc[st] = d;
    }
    if (i == 0) {
        float* dst = att_part + ((size_t)ntb * B_ + b) * C_;
#pragma unroll
        for (int st = 0; st < 16; ++st)
            dst[st * 32 + g] = dacc[st];
    }
}

// ---------------------------------------------------------------------------
// K3f: att-partial reduce + dense1 + BN + ReLU + dense2 + sigmoid.
// One block per batch b (16 blocks, 256 threads).
// ---------------------------------------------------------------------------
__global__ void k3f(const float* __restrict__ att_part,
                    const float* __restrict__ W1,
                    const float* __restrict__ gamma,
                    const float* __restrict__ beta,
                    const float* __restrict__ rmean,
                    const float* __restrict__ rvar,
                    const float* __restrict__ W2,
                    float* __restrict__ a) {
    __shared__ float att_s[C_];
    __shared__ float h_s[CR_];
    const int b = blockIdx.x;
    const int t = threadIdx.x;

    {
        float a0 = 0.f, a1 = 0.f;
#pragma unroll 8
        for (int nb = 0; nb < NTB; ++nb) {
            const float* p = att_part + ((size_t)nb * B_ + b) * C_;
            a0 += p[t];
            a1 += p[t + 256];
        }
        att_s[t]       = a0;
        att_s[t + 256] = a1;
    }
    __syncthreads();

    if (t < CR_) {
        const float* w = W1 + (size_t)t * C_;
        float a0 = 0.f, a1 = 0.f, a2 = 0.f, a3 = 0.f;
#pragma unroll 4
        for (int c = 0; c < C_; c += 4) {
            a0 += w[c + 0] * att_s[c + 0];
            a1 += w[c + 1] * att_s[c + 1];
            a2 += w[c + 2] * att_s[c + 2];
            a3 += w[c + 3] * att_s[c + 3];
        }
        float acc = (a0 + a1) + (a2 + a3);
        float vv = gamma[t] * (acc - rmean[t]) * rsqrtf(rvar[t] + BN_EPS_F) + beta[t];
        h_s[t] = fmaxf(vv, 0.f);
    }
    __syncthreads();
#pragma unroll
    for (int j0 = 0; j0 < C_; j0 += 256) {
        const int j = j0 + t;
        const float* w = W2 + (size_t)j * CR_;
        float a0 = 0.f, a1 = 0.f, a2 = 0.f, a3 = 0.f;
#pragma unroll 4
        for (int k = 0; k < CR_; k += 4) {
            a0 += w[k + 0] * h_s[k + 0];
            a1 += w[k + 1] * h_s[k + 1];
            a2 += w[k + 2] * h_s[k + 2];
            a3 += w[k + 3] * h_s[k + 3];
        }
        float acc = (a0 + a1) + (a2 + a3);
        a[(size_t)b * C_ + j] = 1.f / (1.f + expf(-acc));
    }
}

// ---------------------------------------------------------------------------
// K4: out[b,c,n] = x[b,c,n] * a[b,c].  Block-per-row: a is block-uniform,
// accesses contiguous, NT stores keep x resident in L3.
// ---------------------------------------------------------------------------
__global__ __launch_bounds__(256) void k4_scale(
        const float* __restrict__ x,
        const float* __restrict__ a,
        float* __restrict__ out) {
    const int row = blockIdx.x;          // [0, B*C)
    const float av = a[row];
    const vfloat4* xr = (const vfloat4*)x + (size_t)row * N4_;
    vfloat4* orow     = (vfloat4*)out     + (size_t)row * N4_;
#pragma unroll
    for (int it = 0; it < N4_ / 256; ++it) {   // 4 iters
        const int idx = it * 256 + threadIdx.x;
        vfloat4 ov = xr[idx] * av;
        __builtin_nontemporal_store(ov, &orow[idx]);
    }
}

// ---------------------------------------------------------------------------
extern "C" void kernel_launch(void* const* d_in, const int* in_sizes, int n_in,
                              void* d_out, int out_size, void* d_ws, size_t ws_size,
                              hipStream_t stream) {
    const float* x     = (const float*)d_in[0];
    const float* W1    = (const float*)d_in[1];
    const float* gamma = (const float*)d_in[2];
    const float* beta  = (const float*)d_in[3];
    const float* rmean = (const float*)d_in[4];
    const float* rvar  = (const float*)d_in[5];
    const float* W2    = (const float*)d_in[6];
    float* out = (float*)d_out;

    // Workspace (floats): att_part 64*16*512 = 524288 (2 MiB), a 8192
    float* ws       = (float*)d_ws;
    float* att_part = ws;
    float* a        = att_part + (size_t)NTB * B_ * C_;

    k1f_att<<<dim3(NTB, B_), 256, 0, stream>>>(x, att_part);
    k3f<<<dim3(B_), 256, 0, stream>>>(att_part, W1, gamma, beta, rmean, rvar, W2, a);
    k4_scale<<<dim3(B_ * C_), 256, 0, stream>>>(x, a, out);
}